// Round 1
// baseline (239.480 us; speedup 1.0000x reference)
//
#include <hip/hip_runtime.h>
#include <stdint.h>

typedef __bf16 bf16_t;
typedef __bf16 bf16x8 __attribute__((ext_vector_type(8)));
typedef __bf16 bf16x4 __attribute__((ext_vector_type(4)));
typedef float floatx4 __attribute__((ext_vector_type(4)));

__device__ __forceinline__ void async_copy16(const bf16_t* g, bf16_t* l) {
  __builtin_amdgcn_global_load_lds(
      (const __attribute__((address_space(1))) void*)g,
      (__attribute__((address_space(3))) void*)l, 16, 0, 0);
}

// ---------- converts ----------
struct CvtSeg { const float* s; bf16_t* d; long n; };
struct CvtArgs { CvtSeg seg[5]; };

__global__ void cvt_multi(CvtArgs a) {
  CvtSeg sg = a.seg[blockIdx.y];
#pragma unroll
  for (int it = 0; it < 4; it++) {
    long i = (((long)blockIdx.x + (long)it * 2048) * 256 + threadIdx.x) * 4;
    if (i < sg.n) {
      float4 f = *(const float4*)(sg.s + i);
      bf16x4 o;
      o[0] = (bf16_t)f.x; o[1] = (bf16_t)f.y; o[2] = (bf16_t)f.z; o[3] = (bf16_t)f.w;
      *(bf16x4*)(sg.d + i) = o;
    }
  }
}

// ---------- M-half sum: Mtb = (bf16)(Mh[2b] + Mh[2b+1]) ----------
__global__ void cvt_mhalf(const bf16_t* __restrict__ mh, bf16_t* __restrict__ mt) {
  const long i = ((long)blockIdx.x * 256 + threadIdx.x) * 8;  // 4M elems total
  const long b = i >> 20;              // batch
  const long r = i & ((1L << 20) - 1);
  const bf16_t* h0 = mh + ((b * 2) << 20) + r;
  const bf16_t* h1 = h0 + (1L << 20);
  bf16x8 x0 = *(const bf16x8*)h0;
  bf16x8 x1 = *(const bf16x8*)h1;
  bf16x8 o;
#pragma unroll
  for (int j = 0; j < 8; j++) o[j] = (bf16_t)((float)x0[j] + (float)x1[j]);
  *(bf16x8*)(mt + i) = o;
}

// ---------- fused q / kT / vT: 128x128 tile, LDS dbuf (round-5 proven) ----------
__global__ __launch_bounds__(256, 2) void qkv3(
    const bf16_t* __restrict__ xb,
    const bf16_t* __restrict__ Wq, const bf16_t* __restrict__ Wk, const bf16_t* __restrict__ Wv,
    const float* __restrict__ bq, const float* __restrict__ bk, const float* __restrict__ bv,
    bf16_t* __restrict__ qout, bf16_t* __restrict__ kT, bf16_t* __restrict__ vT) {
  __shared__ bf16_t As[2 * 4096];
  __shared__ bf16_t Bsh[3][2 * 4096];
  const int L = blockIdx.x;
  const int V = (L & 7) * 64 + (L >> 3);
  const int batch = V >> 7;
  const int rr_   = V & 127;
  const int n0 = (rr_ & 7) * 128;
  const int m0 = (rr_ >> 3) * 128;

  const int tid = threadIdx.x, lane = tid & 63, w = tid >> 6;
  const int wr = w >> 1, wc = w & 1, quad = lane >> 4, lm = lane & 15;
  const int ar = lane >> 2;
  const int ak = (((lane & 3) ^ ((ar >> 1) & 3))) * 8;
  const int swz = (lm >> 1) & 3;

  const bf16_t* ag0 = xb + (long)batch * (2048L * 1024) + (long)(m0 + w * 16 + ar) * 1024 + ak;
  const bf16_t* ag1 = ag0 + 64L * 1024;
  const bf16_t* Wp[3] = {Wq, Wk, Wv};
  const bf16_t* bg0[3];
  const bf16_t* bg1[3];
#pragma unroll
  for (int p = 0; p < 3; p++) {
    bg0[p] = Wp[p] + (long)(n0 + w * 16 + ar) * 1024 + ak;
    bg1[p] = bg0[p] + 64L * 1024;
  }

  floatx4 acc[3][4][4];
#pragma unroll
  for (int p = 0; p < 3; p++)
#pragma unroll
    for (int r = 0; r < 4; r++)
#pragma unroll
      for (int c = 0; c < 4; c++)
        acc[p][r][c] = (floatx4){0.f, 0.f, 0.f, 0.f};

  {
    bf16_t* la = As + w * 512;
    async_copy16(ag0, la);
    async_copy16(ag1, la + 2048);
#pragma unroll
    for (int p = 0; p < 3; p++) {
      bf16_t* lb = Bsh[p] + w * 512;
      async_copy16(bg0[p], lb);
      async_copy16(bg1[p], lb + 2048);
    }
  }
  for (int i = 0; i < 32; i++) {
    __syncthreads();
    if (i + 1 < 32) {
      const int buf = (i + 1) & 1, k0 = (i + 1) * 32;
      bf16_t* la = As + buf * 4096 + w * 512;
      async_copy16(ag0 + k0, la);
      async_copy16(ag1 + k0, la + 2048);
#pragma unroll
      for (int p = 0; p < 3; p++) {
        bf16_t* lb = Bsh[p] + buf * 4096 + w * 512;
        async_copy16(bg0[p] + k0, lb);
        async_copy16(bg1[p] + k0, lb + 2048);
      }
    }
    const bf16_t* Ar = As + (i & 1) * 4096;
    bf16x8 afr[4];
#pragma unroll
    for (int r = 0; r < 4; r++)
      afr[r] = *(const bf16x8*)&Ar[(wr * 64 + r * 16 + lm) * 32 + (quad ^ swz) * 8];
#pragma unroll
    for (int p = 0; p < 3; p++) {
      const bf16_t* Br = Bsh[p] + (i & 1) * 4096;
      bf16x8 bfr[4];
#pragma unroll
      for (int c = 0; c < 4; c++)
        bfr[c] = *(const bf16x8*)&Br[(wc * 64 + c * 16 + lm) * 32 + (quad ^ swz) * 8];
#pragma unroll
      for (int r = 0; r < 4; r++)
#pragma unroll
        for (int c = 0; c < 4; c++)
          acc[p][r][c] = __builtin_amdgcn_mfma_f32_16x16x32_bf16(afr[r], bfr[c], acc[p][r][c], 0, 0, 0);
    }
  }

  const int rowBase = m0 + wr * 64, colBase = n0 + wc * 64;
  {
    bf16_t* C = qout + (long)batch * (2048L * 1024);
#pragma unroll
    for (int r = 0; r < 4; r++) {
      const int row = rowBase + r * 16 + quad * 4;
#pragma unroll
      for (int c = 0; c < 4; c++) {
        const int col = colBase + c * 16 + lm;
        const float bv_ = bq[col];
#pragma unroll
        for (int i = 0; i < 4; i++)
          C[(long)(row + i) * 1024 + col] = (bf16_t)(acc[0][r][c][i] + bv_);
      }
    }
  }
#pragma unroll
  for (int p = 1; p < 3; p++) {
    bf16_t* C = ((p == 1) ? kT : vT) + (long)batch * (1024L * 2048);
    const float* bias = (p == 1) ? bk : bv;
#pragma unroll
    for (int r = 0; r < 4; r++) {
      const int row = rowBase + r * 16 + quad * 4;
#pragma unroll
      for (int c = 0; c < 4; c++) {
        const int col = colBase + c * 16 + lm;
        const float bv_ = bias[col];
        bf16x4 pk;
#pragma unroll
        for (int i = 0; i < 4; i++) pk[i] = (bf16_t)(acc[p][r][c][i] + bv_);
        *(bf16x4*)(C + (long)col * 2048 + row) = pk;
      }
    }
  }
}

// ---------- NT GEMM, 128x128 tile, 4x4 acc/wave, BK=32, dbuf LDS, XCD swizzle ----------
// OUT_MODE 0: bf16 row-major; 2: fp32 row-major (+bias).
// N is fixed at 1024 (8 n-tiles). KSPLIT>1: z index = batch*KSPLIT + khalf; C indexed by z.
template<int OUT_MODE, bool HAS_BIAS, int TOTAL, int BPZ, int KSPLIT>
__global__ __launch_bounds__(256) void gemm_nt128(
    const bf16_t* __restrict__ A, const bf16_t* __restrict__ B,
    void* __restrict__ C, const float* __restrict__ bias,
    int lda, int ldb, int nk, long sA, long sB, long sC, int ldc, float alpha) {
  __shared__ bf16_t As[2 * 4096];   // 128 x 32 per buffer
  __shared__ bf16_t Bs[2 * 4096];   // 128 x 32 per buffer
  const int L = blockIdx.x;
  const int V = (L & 7) * (TOTAL / 8) + (L >> 3);
  const int zz = V / BPZ;
  const int r_ = V % BPZ;
  const int batch = zz / KSPLIT;
  const long koff = (long)(zz % KSPLIT) * ((long)nk * 32);
  const int n0 = (r_ & 7) * 128;
  const int m0 = (r_ >> 3) * 128;

  const int tid = threadIdx.x, lane = tid & 63, w = tid >> 6;
  const int wr = w >> 1, wc = w & 1, quad = lane >> 4, lm = lane & 15;
  const int ar = lane >> 2;
  const int ak = (((lane & 3) ^ ((ar >> 1) & 3))) * 8;
  const int swz = (lm >> 1) & 3;

  const bf16_t* Ab = A + (long)batch * sA + koff;
  const bf16_t* Bb = B + (long)batch * sB + koff;
  const bf16_t* ag0 = Ab + (long)(m0 + w * 16 + ar) * lda + ak;
  const bf16_t* ag1 = ag0 + (long)64 * lda;
  const bf16_t* bg0 = Bb + (long)(n0 + w * 16 + ar) * ldb + ak;
  const bf16_t* bg1 = bg0 + (long)64 * ldb;

  floatx4 acc[4][4];
#pragma unroll
  for (int r = 0; r < 4; r++)
#pragma unroll
    for (int c = 0; c < 4; c++) acc[r][c] = (floatx4){0.f, 0.f, 0.f, 0.f};

  {
    async_copy16(ag0, As + w * 512);
    async_copy16(ag1, As + w * 512 + 2048);
    async_copy16(bg0, Bs + w * 512);
    async_copy16(bg1, Bs + w * 512 + 2048);
  }
  for (int i = 0; i < nk; i++) {
    __syncthreads();
    if (i + 1 < nk) {
      const int buf = (i + 1) & 1, k0 = (i + 1) * 32;
      async_copy16(ag0 + k0, As + buf * 4096 + w * 512);
      async_copy16(ag1 + k0, As + buf * 4096 + w * 512 + 2048);
      async_copy16(bg0 + k0, Bs + buf * 4096 + w * 512);
      async_copy16(bg1 + k0, Bs + buf * 4096 + w * 512 + 2048);
    }
    const bf16_t* Ar = As + (i & 1) * 4096;
    const bf16_t* Br = Bs + (i & 1) * 4096;
    bf16x8 afr[4], bfr[4];
#pragma unroll
    for (int r = 0; r < 4; r++)
      afr[r] = *(const bf16x8*)&Ar[(wr * 64 + r * 16 + lm) * 32 + (quad ^ swz) * 8];
#pragma unroll
    for (int c = 0; c < 4; c++)
      bfr[c] = *(const bf16x8*)&Br[(wc * 64 + c * 16 + lm) * 32 + (quad ^ swz) * 8];
#pragma unroll
    for (int r = 0; r < 4; r++)
#pragma unroll
      for (int c = 0; c < 4; c++)
        acc[r][c] = __builtin_amdgcn_mfma_f32_16x16x32_bf16(afr[r], bfr[c], acc[r][c], 0, 0, 0);
  }

  const int rowBase = m0 + wr * 64, colBase = n0 + wc * 64;
  if (OUT_MODE == 0) {
    bf16_t* Cb = (bf16_t*)C + (long)zz * sC;
#pragma unroll
    for (int r = 0; r < 4; r++) {
      const int row = rowBase + r * 16 + quad * 4;
#pragma unroll
      for (int c = 0; c < 4; c++) {
        const int col = colBase + c * 16 + lm;
        const float bv_ = HAS_BIAS ? bias[col] : 0.f;
#pragma unroll
        for (int i = 0; i < 4; i++)
          Cb[(long)(row + i) * ldc + col] = (bf16_t)(acc[r][c][i] * alpha + bv_);
      }
    }
  } else {
    float* Cf = (float*)C + (long)zz * sC;
#pragma unroll
    for (int r = 0; r < 4; r++) {
      const int row = rowBase + r * 16 + quad * 4;
#pragma unroll
      for (int c = 0; c < 4; c++) {
        const int col = colBase + c * 16 + lm;
        const float bv_ = HAS_BIAS ? bias[col] : 0.f;
#pragma unroll
        for (int i = 0; i < 4; i++)
          Cf[(long)(row + i) * ldc + col] = acc[r][c][i] * alpha + bv_;
      }
    }
  }
}

extern "C" void kernel_launch(void* const* d_in, const int* in_sizes, int n_in,
                              void* d_out, int out_size, void* d_ws, size_t ws_size,
                              hipStream_t stream) {
  const float* x  = (const float*)d_in[0];
  const float* Wq = (const float*)d_in[1];
  const float* bq = (const float*)d_in[2];
  const float* Wk = (const float*)d_in[3];
  const float* bk = (const float*)d_in[4];
  const float* Wv = (const float*)d_in[5];
  const float* bv = (const float*)d_in[6];
  const float* Wo = (const float*)d_in[7];
  const float* bo = (const float*)d_in[8];
  float* out = (float*)d_out;

  const long NX = 8192L * 1024;      // 8M elems
  const long NW = 1024L * 1024;      // 1M elems

  bf16_t* ws  = (bf16_t*)d_ws;
  bf16_t* xb  = ws;                  // NX
  bf16_t* Wqb = xb + NX;
  bf16_t* Wkb = Wqb + NW;
  bf16_t* Wvb = Wkb + NW;
  bf16_t* Wob = Wvb + NW;
  bf16_t* qb  = Wob + NW;            // NX
  bf16_t* kT  = qb + NX;             // NX [B][E][S]
  bf16_t* vT  = kT + NX;             // NX [B][E][S]
  // reuse (all stream-ordered):
  bf16_t* Mh  = xb;                  // 8M: [z=b*2+kh][1024*1024], xb dead after qkv3
  bf16_t* Mtb = kT;                  // 4M: [B][e][f], kT dead after Mt gemm
  bf16_t* Pb  = vT;                  // 8M: [B][S][E], vT dead after Mt gemm

  CvtArgs ca;
  ca.seg[0] = {x,  xb,  NX};
  ca.seg[1] = {Wq, Wqb, NW};
  ca.seg[2] = {Wk, Wkb, NW};
  ca.seg[3] = {Wv, Wvb, NW};
  ca.seg[4] = {Wo, Wob, NW};
  cvt_multi<<<dim3(2048, 5), 256, 0, stream>>>(ca);

  // q / kT / vT fused, LDS dbuf (round-5 proven structure)
  qkv3<<<dim3(512), 256, 0, stream>>>(xb, Wqb, Wkb, Wvb, bq, bk, bv, qb, kT, vT);

  // Mt[e,f] = 0.125 * sum_t vT[e,t]*kT[f,t]; split-K=2 (two bf16 half-buffers),
  // 512 blocks (2/CU), 128x128 tile
  gemm_nt128<0, false, 512, 64, 2><<<dim3(512), 256, 0, stream>>>(
      vT, kT, Mh, nullptr, 2048, 2048, 32,
      1024L * 2048, 1024L * 2048, 1024L * 1024, 1024, 0.125f);

  // Mtb = Mh[2b] + Mh[2b+1]
  cvt_mhalf<<<dim3(2048), 256, 0, stream>>>(Mh, Mtb);

  // P[s,e] = sum_f q[s,f] * Mt[e,f]; 512 blocks (2/CU)
  gemm_nt128<0, false, 512, 128, 1><<<dim3(512), 256, 0, stream>>>(
      qb, Mtb, Pb, nullptr, 1024, 1024, 32,
      2048L * 1024, 1024L * 1024, 2048L * 1024, 1024, 1.0f);

  // out[s,i] = sum_e P[s,e] * Wo[i,e] + bo[i]; 512 blocks (2/CU)
  gemm_nt128<2, true, 512, 128, 1><<<dim3(512), 256, 0, stream>>>(
      Pb, Wob, out, bo, 1024, 1024, 32,
      2048L * 1024, 0L, 2048L * 1024, 1024, 1.0f);
}

// Round 2
// 232.380 us; speedup vs baseline: 1.0306x; 1.0306x over previous
//
#include <hip/hip_runtime.h>
#include <stdint.h>

typedef __bf16 bf16_t;
typedef __bf16 bf16x8 __attribute__((ext_vector_type(8)));
typedef __bf16 bf16x4 __attribute__((ext_vector_type(4)));
typedef float floatx4 __attribute__((ext_vector_type(4)));

__device__ __forceinline__ void async_copy16(const bf16_t* g, bf16_t* l) {
  __builtin_amdgcn_global_load_lds(
      (const __attribute__((address_space(1))) void*)g,
      (__attribute__((address_space(3))) void*)l, 16, 0, 0);
}

// ---------- converts ----------
struct CvtSeg { const float* s; bf16_t* d; long n; };
struct CvtArgs { CvtSeg seg[5]; };

__global__ void cvt_multi(CvtArgs a) {
  CvtSeg sg = a.seg[blockIdx.y];
#pragma unroll
  for (int it = 0; it < 4; it++) {
    long i = (((long)blockIdx.x + (long)it * 2048) * 256 + threadIdx.x) * 4;
    if (i < sg.n) {
      float4 f = *(const float4*)(sg.s + i);
      bf16x4 o;
      o[0] = (bf16_t)f.x; o[1] = (bf16_t)f.y; o[2] = (bf16_t)f.z; o[3] = (bf16_t)f.w;
      *(bf16x4*)(sg.d + i) = o;
    }
  }
}

// ---------- split-K half sum: mt = (bf16)(mh[2b] + mh[2b+1]) ----------
__global__ void cvt_mhalf(const bf16_t* __restrict__ mh, bf16_t* __restrict__ mt) {
  const long i = ((long)blockIdx.x * 256 + threadIdx.x) * 8;  // 4M elems total
  const long b = i >> 20;              // output matrix index
  const long r = i & ((1L << 20) - 1);
  const bf16_t* h0 = mh + ((b * 2) << 20) + r;
  const bf16_t* h1 = h0 + (1L << 20);
  bf16x8 x0 = *(const bf16x8*)h0;
  bf16x8 x1 = *(const bf16x8*)h1;
  bf16x8 o;
#pragma unroll
  for (int j = 0; j < 8; j++) o[j] = (bf16_t)((float)x0[j] + (float)x1[j]);
  *(bf16x8*)(mt + i) = o;
}

// ---------- fused q / kT / vT: 128x128 tile, LDS dbuf (round-5 proven) ----------
__global__ __launch_bounds__(256, 2) void qkv3(
    const bf16_t* __restrict__ xb,
    const bf16_t* __restrict__ Wq, const bf16_t* __restrict__ Wk, const bf16_t* __restrict__ Wv,
    const float* __restrict__ bq, const float* __restrict__ bk, const float* __restrict__ bv,
    bf16_t* __restrict__ qout, bf16_t* __restrict__ kT, bf16_t* __restrict__ vT) {
  __shared__ bf16_t As[2 * 4096];
  __shared__ bf16_t Bsh[3][2 * 4096];
  const int L = blockIdx.x;
  const int V = (L & 7) * 64 + (L >> 3);
  const int batch = V >> 7;
  const int rr_   = V & 127;
  const int n0 = (rr_ & 7) * 128;
  const int m0 = (rr_ >> 3) * 128;

  const int tid = threadIdx.x, lane = tid & 63, w = tid >> 6;
  const int wr = w >> 1, wc = w & 1, quad = lane >> 4, lm = lane & 15;
  const int ar = lane >> 2;
  const int ak = (((lane & 3) ^ ((ar >> 1) & 3))) * 8;
  const int swz = (lm >> 1) & 3;

  const bf16_t* ag0 = xb + (long)batch * (2048L * 1024) + (long)(m0 + w * 16 + ar) * 1024 + ak;
  const bf16_t* ag1 = ag0 + 64L * 1024;
  const bf16_t* Wp[3] = {Wq, Wk, Wv};
  const bf16_t* bg0[3];
  const bf16_t* bg1[3];
#pragma unroll
  for (int p = 0; p < 3; p++) {
    bg0[p] = Wp[p] + (long)(n0 + w * 16 + ar) * 1024 + ak;
    bg1[p] = bg0[p] + 64L * 1024;
  }

  floatx4 acc[3][4][4];
#pragma unroll
  for (int p = 0; p < 3; p++)
#pragma unroll
    for (int r = 0; r < 4; r++)
#pragma unroll
      for (int c = 0; c < 4; c++)
        acc[p][r][c] = (floatx4){0.f, 0.f, 0.f, 0.f};

  {
    bf16_t* la = As + w * 512;
    async_copy16(ag0, la);
    async_copy16(ag1, la + 2048);
#pragma unroll
    for (int p = 0; p < 3; p++) {
      bf16_t* lb = Bsh[p] + w * 512;
      async_copy16(bg0[p], lb);
      async_copy16(bg1[p], lb + 2048);
    }
  }
  for (int i = 0; i < 32; i++) {
    __syncthreads();
    if (i + 1 < 32) {
      const int buf = (i + 1) & 1, k0 = (i + 1) * 32;
      bf16_t* la = As + buf * 4096 + w * 512;
      async_copy16(ag0 + k0, la);
      async_copy16(ag1 + k0, la + 2048);
#pragma unroll
      for (int p = 0; p < 3; p++) {
        bf16_t* lb = Bsh[p] + buf * 4096 + w * 512;
        async_copy16(bg0[p] + k0, lb);
        async_copy16(bg1[p] + k0, lb + 2048);
      }
    }
    const bf16_t* Ar = As + (i & 1) * 4096;
    bf16x8 afr[4];
#pragma unroll
    for (int r = 0; r < 4; r++)
      afr[r] = *(const bf16x8*)&Ar[(wr * 64 + r * 16 + lm) * 32 + (quad ^ swz) * 8];
#pragma unroll
    for (int p = 0; p < 3; p++) {
      const bf16_t* Br = Bsh[p] + (i & 1) * 4096;
      bf16x8 bfr[4];
#pragma unroll
      for (int c = 0; c < 4; c++)
        bfr[c] = *(const bf16x8*)&Br[(wc * 64 + c * 16 + lm) * 32 + (quad ^ swz) * 8];
#pragma unroll
      for (int r = 0; r < 4; r++)
#pragma unroll
        for (int c = 0; c < 4; c++)
          acc[p][r][c] = __builtin_amdgcn_mfma_f32_16x16x32_bf16(afr[r], bfr[c], acc[p][r][c], 0, 0, 0);
    }
  }

  const int rowBase = m0 + wr * 64, colBase = n0 + wc * 64;
  {
    bf16_t* C = qout + (long)batch * (2048L * 1024);
#pragma unroll
    for (int r = 0; r < 4; r++) {
      const int row = rowBase + r * 16 + quad * 4;
#pragma unroll
      for (int c = 0; c < 4; c++) {
        const int col = colBase + c * 16 + lm;
        const float bv_ = bq[col];
#pragma unroll
        for (int i = 0; i < 4; i++)
          C[(long)(row + i) * 1024 + col] = (bf16_t)(acc[0][r][c][i] + bv_);
      }
    }
  }
#pragma unroll
  for (int p = 1; p < 3; p++) {
    bf16_t* C = ((p == 1) ? kT : vT) + (long)batch * (1024L * 2048);
    const float* bias = (p == 1) ? bk : bv;
#pragma unroll
    for (int r = 0; r < 4; r++) {
      const int row = rowBase + r * 16 + quad * 4;
#pragma unroll
      for (int c = 0; c < 4; c++) {
        const int col = colBase + c * 16 + lm;
        const float bv_ = bias[col];
        bf16x4 pk;
#pragma unroll
        for (int i = 0; i < 4; i++) pk[i] = (bf16_t)(acc[p][r][c][i] + bv_);
        *(bf16x4*)(C + (long)col * 2048 + row) = pk;
      }
    }
  }
}

// ---------- NT GEMM, 128x128 tile, 4-buffer LDS, counted-vmcnt pipeline ----------
// OUT_MODE 0: bf16 row-major; 2: fp32 row-major (+bias).
// N fixed at 1024 (8 n-tiles per z). KSPLIT>1: z = batch*KSPLIT + kpart; C indexed by z.
// Pipeline: prefetch depth 2, 4 LDS buffers, s_waitcnt vmcnt(8) + raw s_barrier
// (never drains to 0 in steady state -> K-step load latency stays hidden).
template<int OUT_MODE, bool HAS_BIAS, int TOTAL, int BPZ, int KSPLIT>
__global__ __launch_bounds__(256) void gemm_nt128(
    const bf16_t* __restrict__ A, const bf16_t* __restrict__ B,
    void* __restrict__ C, const float* __restrict__ bias,
    int lda, int ldb, int nk, long sA, long sB, long sC, int ldc, float alpha) {
  __shared__ bf16_t As[4 * 4096];   // 4 bufs x 128x32
  __shared__ bf16_t Bs[4 * 4096];
  const int L = blockIdx.x;
  const int V = (L & 7) * (TOTAL / 8) + (L >> 3);
  const int zz = V / BPZ;
  const int r_ = V % BPZ;
  const int batch = zz / KSPLIT;
  const long koff = (long)(zz % KSPLIT) * ((long)nk * 32);
  const int n0 = (r_ & 7) * 128;
  const int m0 = (r_ >> 3) * 128;

  const int tid = threadIdx.x, lane = tid & 63, w = tid >> 6;
  const int wr = w >> 1, wc = w & 1, quad = lane >> 4, lm = lane & 15;
  const int ar = lane >> 2;
  const int ak = (((lane & 3) ^ ((ar >> 1) & 3))) * 8;
  const int swz = (lm >> 1) & 3;

  const bf16_t* Ab = A + (long)batch * sA + koff;
  const bf16_t* Bb = B + (long)batch * sB + koff;
  const bf16_t* ag0 = Ab + (long)(m0 + w * 16 + ar) * lda + ak;
  const bf16_t* ag1 = ag0 + (long)64 * lda;
  const bf16_t* bg0 = Bb + (long)(n0 + w * 16 + ar) * ldb + ak;
  const bf16_t* bg1 = bg0 + (long)64 * ldb;

  auto STAGE = [&](int t, int buf) {
    const int k0 = t * 32;
    async_copy16(ag0 + k0, As + buf * 4096 + w * 512);
    async_copy16(ag1 + k0, As + buf * 4096 + w * 512 + 2048);
    async_copy16(bg0 + k0, Bs + buf * 4096 + w * 512);
    async_copy16(bg1 + k0, Bs + buf * 4096 + w * 512 + 2048);
  };

  floatx4 acc[4][4];
#pragma unroll
  for (int r = 0; r < 4; r++)
#pragma unroll
    for (int c = 0; c < 4; c++) acc[r][c] = (floatx4){0.f, 0.f, 0.f, 0.f};

  STAGE(0, 0);
  STAGE(1, 1);
  for (int i = 0; i < nk; i++) {
    if (i + 2 < nk) {
      STAGE(i + 2, (i + 2) & 3);
      // my 4 loads of tile i are the oldest beyond {tile i+1, tile i+2} = 8
      asm volatile("s_waitcnt vmcnt(8)" ::: "memory");
    } else if (i + 1 < nk) {
      asm volatile("s_waitcnt vmcnt(4)" ::: "memory");
    } else {
      asm volatile("s_waitcnt vmcnt(0)" ::: "memory");
    }
    __builtin_amdgcn_s_barrier();
    asm volatile("" ::: "memory");  // keep ds_reads below the barrier
    const bf16_t* Ar = As + (i & 3) * 4096;
    const bf16_t* Br = Bs + (i & 3) * 4096;
    bf16x8 afr[4], bfr[4];
#pragma unroll
    for (int r = 0; r < 4; r++)
      afr[r] = *(const bf16x8*)&Ar[(wr * 64 + r * 16 + lm) * 32 + (quad ^ swz) * 8];
#pragma unroll
    for (int c = 0; c < 4; c++)
      bfr[c] = *(const bf16x8*)&Br[(wc * 64 + c * 16 + lm) * 32 + (quad ^ swz) * 8];
#pragma unroll
    for (int r = 0; r < 4; r++)
#pragma unroll
      for (int c = 0; c < 4; c++)
        acc[r][c] = __builtin_amdgcn_mfma_f32_16x16x32_bf16(afr[r], bfr[c], acc[r][c], 0, 0, 0);
  }

  const int rowBase = m0 + wr * 64, colBase = n0 + wc * 64;
  if (OUT_MODE == 0) {
    bf16_t* Cb = (bf16_t*)C + (long)zz * sC;
#pragma unroll
    for (int r = 0; r < 4; r++) {
      const int row = rowBase + r * 16 + quad * 4;
#pragma unroll
      for (int c = 0; c < 4; c++) {
        const int col = colBase + c * 16 + lm;
        const float bv_ = HAS_BIAS ? bias[col] : 0.f;
#pragma unroll
        for (int i = 0; i < 4; i++)
          Cb[(long)(row + i) * ldc + col] = (bf16_t)(acc[r][c][i] * alpha + bv_);
      }
    }
  } else {
    float* Cf = (float*)C + (long)zz * sC;
#pragma unroll
    for (int r = 0; r < 4; r++) {
      const int row = rowBase + r * 16 + quad * 4;
#pragma unroll
      for (int c = 0; c < 4; c++) {
        const int col = colBase + c * 16 + lm;
        const float bv_ = HAS_BIAS ? bias[col] : 0.f;
#pragma unroll
        for (int i = 0; i < 4; i++)
          Cf[(long)(row + i) * ldc + col] = acc[r][c][i] * alpha + bv_;
      }
    }
  }
}

extern "C" void kernel_launch(void* const* d_in, const int* in_sizes, int n_in,
                              void* d_out, int out_size, void* d_ws, size_t ws_size,
                              hipStream_t stream) {
  const float* x  = (const float*)d_in[0];
  const float* Wq = (const float*)d_in[1];
  const float* bq = (const float*)d_in[2];
  const float* Wk = (const float*)d_in[3];
  const float* bk = (const float*)d_in[4];
  const float* Wv = (const float*)d_in[5];
  const float* bv = (const float*)d_in[6];
  const float* Wo = (const float*)d_in[7];
  const float* bo = (const float*)d_in[8];
  float* out = (float*)d_out;

  const long NX = 8192L * 1024;      // 8M elems
  const long NW = 1024L * 1024;      // 1M elems

  bf16_t* ws  = (bf16_t*)d_ws;
  bf16_t* xb  = ws;                  // NX
  bf16_t* Wqb = xb + NX;
  bf16_t* Wkb = Wqb + NW;
  bf16_t* Wvb = Wkb + NW;
  bf16_t* Wob = Wvb + NW;
  bf16_t* qb  = Wob + NW;            // NX
  bf16_t* kT  = qb + NX;             // NX [B][E][S]
  bf16_t* vT  = kT + NX;             // NX [B][E][S]
  // reuse (stream-ordered):
  bf16_t* Mh   = xb;                 // 8M: [z=b*2+kh][f][e], xb dead after qkv3
  bf16_t* MtTb = kT;                 // 4M: [B][f][e], kT dead after MtT gemm
  bf16_t* Gb   = vT;                 // 4M: [B][i][f], vT dead after MtT gemm

  CvtArgs ca;
  ca.seg[0] = {x,  xb,  NX};
  ca.seg[1] = {Wq, Wqb, NW};
  ca.seg[2] = {Wk, Wkb, NW};
  ca.seg[3] = {Wv, Wvb, NW};
  ca.seg[4] = {Wo, Wob, NW};
  cvt_multi<<<dim3(2048, 5), 256, 0, stream>>>(ca);

  // q / kT / vT fused, LDS dbuf (round-5 proven structure)
  qkv3<<<dim3(512), 256, 0, stream>>>(xb, Wqb, Wkb, Wvb, bq, bk, bv, qb, kT, vT);

  // MtT[f,e] = 0.125 * sum_t kT[f,t]*vT[e,t]; split-K=2, 512 blocks (2/CU)
  gemm_nt128<0, false, 512, 64, 2><<<dim3(512), 256, 0, stream>>>(
      kT, vT, Mh, nullptr, 2048, 2048, 32,
      1024L * 2048, 1024L * 2048, 1024L * 1024, 1024, 0.125f);

  // MtTb = Mh[2b] + Mh[2b+1]
  cvt_mhalf<<<dim3(2048), 256, 0, stream>>>(Mh, MtTb);

  // G[i,f] = sum_e Wo[i,e] * MtT[f,e]; 256 blocks (1/CU), latency-tolerant loop
  gemm_nt128<0, false, 256, 64, 1><<<dim3(256), 256, 0, stream>>>(
      Wob, MtTb, Gb, nullptr, 1024, 1024, 32,
      0L, 1024L * 1024, 1024L * 1024, 1024, 1.0f);

  // out[s,i] = sum_f q[s,f] * G[i,f] + bo[i]; 512 blocks (2/CU)
  gemm_nt128<2, true, 512, 128, 1><<<dim3(512), 256, 0, stream>>>(
      qb, Gb, out, bo, 1024, 1024, 32,
      2048L * 1024, 1024L * 1024, 2048L * 1024, 1024, 1.0f);
}

// Round 3
// 231.679 us; speedup vs baseline: 1.0337x; 1.0030x over previous
//
#include <hip/hip_runtime.h>
#include <stdint.h>

typedef __bf16 bf16_t;
typedef __bf16 bf16x8 __attribute__((ext_vector_type(8)));
typedef __bf16 bf16x4 __attribute__((ext_vector_type(4)));
typedef float floatx4 __attribute__((ext_vector_type(4)));

__device__ __forceinline__ void async_copy16(const bf16_t* g, bf16_t* l) {
  __builtin_amdgcn_global_load_lds(
      (const __attribute__((address_space(1))) void*)g,
      (__attribute__((address_space(3))) void*)l, 16, 0, 0);
}

// ---------- converts ----------
struct CvtSeg { const float* s; bf16_t* d; long n; };
struct CvtArgs { CvtSeg seg[5]; };

__global__ void cvt_multi(CvtArgs a) {
  CvtSeg sg = a.seg[blockIdx.y];
#pragma unroll
  for (int it = 0; it < 4; it++) {
    long i = (((long)blockIdx.x + (long)it * 2048) * 256 + threadIdx.x) * 4;
    if (i < sg.n) {
      float4 f = *(const float4*)(sg.s + i);
      bf16x4 o;
      o[0] = (bf16_t)f.x; o[1] = (bf16_t)f.y; o[2] = (bf16_t)f.z; o[3] = (bf16_t)f.w;
      *(bf16x4*)(sg.d + i) = o;
    }
  }
}

// ---------- fused q / kT / vT: 128x128 tile, LDS dbuf (round-5 proven) ----------
__global__ __launch_bounds__(256, 2) void qkv3(
    const bf16_t* __restrict__ xb,
    const bf16_t* __restrict__ Wq, const bf16_t* __restrict__ Wk, const bf16_t* __restrict__ Wv,
    const float* __restrict__ bq, const float* __restrict__ bk, const float* __restrict__ bv,
    bf16_t* __restrict__ qout, bf16_t* __restrict__ kT, bf16_t* __restrict__ vT) {
  __shared__ bf16_t As[2 * 4096];
  __shared__ bf16_t Bsh[3][2 * 4096];
  const int L = blockIdx.x;
  const int V = (L & 7) * 64 + (L >> 3);
  const int batch = V >> 7;
  const int rr_   = V & 127;
  const int n0 = (rr_ & 7) * 128;
  const int m0 = (rr_ >> 3) * 128;

  const int tid = threadIdx.x, lane = tid & 63, w = tid >> 6;
  const int wr = w >> 1, wc = w & 1, quad = lane >> 4, lm = lane & 15;
  const int ar = lane >> 2;
  const int ak = (((lane & 3) ^ ((ar >> 1) & 3))) * 8;
  const int swz = (lm >> 1) & 3;

  const bf16_t* ag0 = xb + (long)batch * (2048L * 1024) + (long)(m0 + w * 16 + ar) * 1024 + ak;
  const bf16_t* ag1 = ag0 + 64L * 1024;
  const bf16_t* Wp[3] = {Wq, Wk, Wv};
  const bf16_t* bg0[3];
  const bf16_t* bg1[3];
#pragma unroll
  for (int p = 0; p < 3; p++) {
    bg0[p] = Wp[p] + (long)(n0 + w * 16 + ar) * 1024 + ak;
    bg1[p] = bg0[p] + 64L * 1024;
  }

  floatx4 acc[3][4][4];
#pragma unroll
  for (int p = 0; p < 3; p++)
#pragma unroll
    for (int r = 0; r < 4; r++)
#pragma unroll
      for (int c = 0; c < 4; c++)
        acc[p][r][c] = (floatx4){0.f, 0.f, 0.f, 0.f};

  {
    bf16_t* la = As + w * 512;
    async_copy16(ag0, la);
    async_copy16(ag1, la + 2048);
#pragma unroll
    for (int p = 0; p < 3; p++) {
      bf16_t* lb = Bsh[p] + w * 512;
      async_copy16(bg0[p], lb);
      async_copy16(bg1[p], lb + 2048);
    }
  }
  for (int i = 0; i < 32; i++) {
    __syncthreads();
    if (i + 1 < 32) {
      const int buf = (i + 1) & 1, k0 = (i + 1) * 32;
      bf16_t* la = As + buf * 4096 + w * 512;
      async_copy16(ag0 + k0, la);
      async_copy16(ag1 + k0, la + 2048);
#pragma unroll
      for (int p = 0; p < 3; p++) {
        bf16_t* lb = Bsh[p] + buf * 4096 + w * 512;
        async_copy16(bg0[p] + k0, lb);
        async_copy16(bg1[p] + k0, lb + 2048);
      }
    }
    const bf16_t* Ar = As + (i & 1) * 4096;
    bf16x8 afr[4];
#pragma unroll
    for (int r = 0; r < 4; r++)
      afr[r] = *(const bf16x8*)&Ar[(wr * 64 + r * 16 + lm) * 32 + (quad ^ swz) * 8];
#pragma unroll
    for (int p = 0; p < 3; p++) {
      const bf16_t* Br = Bsh[p] + (i & 1) * 4096;
      bf16x8 bfr[4];
#pragma unroll
      for (int c = 0; c < 4; c++)
        bfr[c] = *(const bf16x8*)&Br[(wc * 64 + c * 16 + lm) * 32 + (quad ^ swz) * 8];
#pragma unroll
      for (int r = 0; r < 4; r++)
#pragma unroll
        for (int c = 0; c < 4; c++)
          acc[p][r][c] = __builtin_amdgcn_mfma_f32_16x16x32_bf16(afr[r], bfr[c], acc[p][r][c], 0, 0, 0);
    }
  }

  const int rowBase = m0 + wr * 64, colBase = n0 + wc * 64;
  {
    bf16_t* C = qout + (long)batch * (2048L * 1024);
#pragma unroll
    for (int r = 0; r < 4; r++) {
      const int row = rowBase + r * 16 + quad * 4;
#pragma unroll
      for (int c = 0; c < 4; c++) {
        const int col = colBase + c * 16 + lm;
        const float bv_ = bq[col];
#pragma unroll
        for (int i = 0; i < 4; i++)
          C[(long)(row + i) * 1024 + col] = (bf16_t)(acc[0][r][c][i] + bv_);
      }
    }
  }
#pragma unroll
  for (int p = 1; p < 3; p++) {
    bf16_t* C = ((p == 1) ? kT : vT) + (long)batch * (1024L * 2048);
    const float* bias = (p == 1) ? bk : bv;
#pragma unroll
    for (int r = 0; r < 4; r++) {
      const int row = rowBase + r * 16 + quad * 4;
#pragma unroll
      for (int c = 0; c < 4; c++) {
        const int col = colBase + c * 16 + lm;
        const float bv_ = bias[col];
        bf16x4 pk;
#pragma unroll
        for (int i = 0; i < 4; i++) pk[i] = (bf16_t)(acc[p][r][c][i] + bv_);
        *(bf16x4*)(C + (long)col * 2048 + row) = pk;
      }
    }
  }
}

// ---------- NT GEMM, 128x128 tile, WAVE-PRIVATE barrier-free pipeline ----------
// Each wave stages its own 64x32 A-half and 64x32 B-half into a private 16KB LDS
// slice (2 bufs x (2048 A + 2048 B) elems). No cross-wave LDS sharing -> NO
// s_barrier anywhere. Per-wave counted vmcnt double-buffer:
//   STAGE(i+1) -> buf^1 (8 loads); s_waitcnt vmcnt(8) ensures tile i landed.
// Race-free by per-wave program order: buf^1's previous reads (tile i-1) were
// consumed by MFMA(i-1) before STAGE(i+1) issues.
// OUT_MODE 0: bf16 row-major; 2: fp32 row-major (+bias). N fixed at 1024.
template<int OUT_MODE, bool HAS_BIAS, int TOTAL, int BPZ>
__global__ __launch_bounds__(256) void gemm_wp(
    const bf16_t* __restrict__ A, const bf16_t* __restrict__ B,
    void* __restrict__ C, const float* __restrict__ bias,
    int lda, int ldb, int nk, long sA, long sB, long sC, int ldc, float alpha) {
  __shared__ bf16_t Ls[4 * 8192];   // 4 waves x (2 bufs x 4096 elems) = 64KB
  const int L = blockIdx.x;
  const int V = (L & 7) * (TOTAL / 8) + (L >> 3);
  const int batch = V / BPZ;
  const int r_ = V % BPZ;
  const int n0 = (r_ & 7) * 128;
  const int m0 = (r_ >> 3) * 128;

  const int tid = threadIdx.x, lane = tid & 63, w = tid >> 6;
  const int wr = w >> 1, wc = w & 1, quad = lane >> 4, lm = lane & 15;
  const int ar = lane >> 2;
  const int ak = (((lane & 3) ^ ((ar >> 1) & 3))) * 8;
  const int swz = (lm >> 1) & 3;

  bf16_t* Lw = Ls + w * 8192;
  const bf16_t* Ab = A + (long)batch * sA;
  const bf16_t* Bb = B + (long)batch * sB;
  const bf16_t* agA = Ab + (long)(m0 + wr * 64 + ar) * lda + ak;
  const bf16_t* agB = Bb + (long)(n0 + wc * 64 + ar) * ldb + ak;

  auto STAGE = [&](int t, int b) {
    const int k0 = t * 32;
    bf16_t* d = Lw + b * 4096;
#pragma unroll
    for (int j = 0; j < 4; j++)
      async_copy16(agA + (long)j * 16 * lda + k0, d + j * 512);
#pragma unroll
    for (int j = 0; j < 4; j++)
      async_copy16(agB + (long)j * 16 * ldb + k0, d + 2048 + j * 512);
  };

  floatx4 acc[4][4];
#pragma unroll
  for (int r = 0; r < 4; r++)
#pragma unroll
    for (int c = 0; c < 4; c++) acc[r][c] = (floatx4){0.f, 0.f, 0.f, 0.f};

  STAGE(0, 0);
  for (int i = 0; i < nk; i++) {
    if (i + 1 < nk) {
      STAGE(i + 1, (i + 1) & 1);
      asm volatile("s_waitcnt vmcnt(8)" ::: "memory");  // tile i's 8 loads done
    } else {
      asm volatile("s_waitcnt vmcnt(0)" ::: "memory");
    }
    const bf16_t* Aw = Lw + (i & 1) * 4096;
    const bf16_t* Bw = Aw + 2048;
    bf16x8 afr[4], bfr[4];
#pragma unroll
    for (int r = 0; r < 4; r++)
      afr[r] = *(const bf16x8*)&Aw[(r * 16 + lm) * 32 + (quad ^ swz) * 8];
#pragma unroll
    for (int c = 0; c < 4; c++)
      bfr[c] = *(const bf16x8*)&Bw[(c * 16 + lm) * 32 + (quad ^ swz) * 8];
#pragma unroll
    for (int r = 0; r < 4; r++)
#pragma unroll
      for (int c = 0; c < 4; c++)
        acc[r][c] = __builtin_amdgcn_mfma_f32_16x16x32_bf16(afr[r], bfr[c], acc[r][c], 0, 0, 0);
  }

  const int rowBase = m0 + wr * 64, colBase = n0 + wc * 64;
  if (OUT_MODE == 0) {
    bf16_t* Cb = (bf16_t*)C + (long)batch * sC;
#pragma unroll
    for (int r = 0; r < 4; r++) {
      const int row = rowBase + r * 16 + quad * 4;
#pragma unroll
      for (int c = 0; c < 4; c++) {
        const int col = colBase + c * 16 + lm;
        const float bv_ = HAS_BIAS ? bias[col] : 0.f;
#pragma unroll
        for (int i = 0; i < 4; i++)
          Cb[(long)(row + i) * ldc + col] = (bf16_t)(acc[r][c][i] * alpha + bv_);
      }
    }
  } else {
    float* Cf = (float*)C + (long)batch * sC;
#pragma unroll
    for (int r = 0; r < 4; r++) {
      const int row = rowBase + r * 16 + quad * 4;
#pragma unroll
      for (int c = 0; c < 4; c++) {
        const int col = colBase + c * 16 + lm;
        const float bv_ = HAS_BIAS ? bias[col] : 0.f;
#pragma unroll
        for (int i = 0; i < 4; i++)
          Cf[(long)(row + i) * ldc + col] = acc[r][c][i] * alpha + bv_;
      }
    }
  }
}

extern "C" void kernel_launch(void* const* d_in, const int* in_sizes, int n_in,
                              void* d_out, int out_size, void* d_ws, size_t ws_size,
                              hipStream_t stream) {
  const float* x  = (const float*)d_in[0];
  const float* Wq = (const float*)d_in[1];
  const float* bq = (const float*)d_in[2];
  const float* Wk = (const float*)d_in[3];
  const float* bk = (const float*)d_in[4];
  const float* Wv = (const float*)d_in[5];
  const float* bv = (const float*)d_in[6];
  const float* Wo = (const float*)d_in[7];
  const float* bo = (const float*)d_in[8];
  float* out = (float*)d_out;

  const long NX = 8192L * 1024;      // 8M elems
  const long NW = 1024L * 1024;      // 1M elems

  bf16_t* ws  = (bf16_t*)d_ws;
  bf16_t* xb  = ws;                  // NX
  bf16_t* Wqb = xb + NX;
  bf16_t* Wkb = Wqb + NW;
  bf16_t* Wvb = Wkb + NW;
  bf16_t* Wob = Wvb + NW;
  bf16_t* qb  = Wob + NW;            // NX
  bf16_t* kT  = qb + NX;             // NX [B][E][S]
  bf16_t* vT  = kT + NX;             // NX [B][E][S]
  // reuse (stream-ordered):
  bf16_t* MtTb = xb;                 // 4M: [B][f][e], xb dead after qkv3
  bf16_t* Gb   = vT;                 // 4M: [B][i][f], vT dead after Mt gemm

  CvtArgs ca;
  ca.seg[0] = {x,  xb,  NX};
  ca.seg[1] = {Wq, Wqb, NW};
  ca.seg[2] = {Wk, Wkb, NW};
  ca.seg[3] = {Wv, Wvb, NW};
  ca.seg[4] = {Wo, Wob, NW};
  cvt_multi<<<dim3(2048, 5), 256, 0, stream>>>(ca);

  // q / kT / vT fused, LDS dbuf (round-5 proven structure)
  qkv3<<<dim3(512), 256, 0, stream>>>(xb, Wqb, Wkb, Wvb, bq, bk, bv, qb, kT, vT);

  // MtT[f,e] = 0.125 * sum_t kT[f,t]*vT[e,t]; K=2048 (nk=64), 256 blocks (1/CU)
  gemm_wp<0, false, 256, 64><<<dim3(256), 256, 0, stream>>>(
      kT, vT, MtTb, nullptr, 2048, 2048, 64,
      1024L * 2048, 1024L * 2048, 1024L * 1024, 1024, 0.125f);

  // G[i,f] = sum_e Wo[i,e] * MtT[f,e]; 256 blocks (1/CU)
  gemm_wp<0, false, 256, 64><<<dim3(256), 256, 0, stream>>>(
      Wob, MtTb, Gb, nullptr, 1024, 1024, 32,
      0L, 1024L * 1024, 1024L * 1024, 1024, 1.0f);

  // out[s,i] = sum_f q[s,f] * G[i,f] + bo[i]; 512 blocks (2/CU)
  gemm_wp<2, true, 512, 128><<<dim3(512), 256, 0, stream>>>(
      qb, Gb, out, bo, 1024, 1024, 32,
      2048L * 1024, 1024L * 1024, 2048L * 1024, 1024, 1.0f);
}

// Round 5
// 227.262 us; speedup vs baseline: 1.0538x; 1.0194x over previous
//
#include <hip/hip_runtime.h>
#include <stdint.h>

typedef __bf16 bf16_t;
typedef __bf16 bf16x8 __attribute__((ext_vector_type(8)));
typedef __bf16 bf16x4 __attribute__((ext_vector_type(4)));
typedef float floatx4 __attribute__((ext_vector_type(4)));

__device__ __forceinline__ void async_copy16(const bf16_t* g, bf16_t* l) {
  __builtin_amdgcn_global_load_lds(
      (const __attribute__((address_space(1))) void*)g,
      (__attribute__((address_space(3))) void*)l, 16, 0, 0);
}

// ---------- converts ----------
struct CvtSeg { const float* s; bf16_t* d; long n; };
struct CvtArgs { CvtSeg seg[5]; };

__global__ void cvt_multi(CvtArgs a) {
  CvtSeg sg = a.seg[blockIdx.y];
#pragma unroll
  for (int it = 0; it < 4; it++) {
    long i = (((long)blockIdx.x + (long)it * 2048) * 256 + threadIdx.x) * 4;
    if (i < sg.n) {
      float4 f = *(const float4*)(sg.s + i);
      bf16x4 o;
      o[0] = (bf16_t)f.x; o[1] = (bf16_t)f.y; o[2] = (bf16_t)f.z; o[3] = (bf16_t)f.w;
      *(bf16x4*)(sg.d + i) = o;
    }
  }
}

// ---------- fused q / kT / vT: 128x128 tile, LDS dbuf (round-5 proven) ----------
__global__ __launch_bounds__(256, 2) void qkv3(
    const bf16_t* __restrict__ xb,
    const bf16_t* __restrict__ Wq, const bf16_t* __restrict__ Wk, const bf16_t* __restrict__ Wv,
    const float* __restrict__ bq, const float* __restrict__ bk, const float* __restrict__ bv,
    bf16_t* __restrict__ qout, bf16_t* __restrict__ kT, bf16_t* __restrict__ vT) {
  __shared__ bf16_t As[2 * 4096];
  __shared__ bf16_t Bsh[3][2 * 4096];
  const int L = blockIdx.x;
  const int V = (L & 7) * 64 + (L >> 3);
  const int batch = V >> 7;
  const int rr_   = V & 127;
  const int n0 = (rr_ & 7) * 128;
  const int m0 = (rr_ >> 3) * 128;

  const int tid = threadIdx.x, lane = tid & 63, w = tid >> 6;
  const int wr = w >> 1, wc = w & 1, quad = lane >> 4, lm = lane & 15;
  const int ar = lane >> 2;
  const int ak = (((lane & 3) ^ ((ar >> 1) & 3))) * 8;
  const int swz = (lm >> 1) & 3;

  const bf16_t* ag0 = xb + (long)batch * (2048L * 1024) + (long)(m0 + w * 16 + ar) * 1024 + ak;
  const bf16_t* ag1 = ag0 + 64L * 1024;
  const bf16_t* Wp[3] = {Wq, Wk, Wv};
  const bf16_t* bg0[3];
  const bf16_t* bg1[3];
#pragma unroll
  for (int p = 0; p < 3; p++) {
    bg0[p] = Wp[p] + (long)(n0 + w * 16 + ar) * 1024 + ak;
    bg1[p] = bg0[p] + 64L * 1024;
  }

  floatx4 acc[3][4][4];
#pragma unroll
  for (int p = 0; p < 3; p++)
#pragma unroll
    for (int r = 0; r < 4; r++)
#pragma unroll
      for (int c = 0; c < 4; c++)
        acc[p][r][c] = (floatx4){0.f, 0.f, 0.f, 0.f};

  {
    bf16_t* la = As + w * 512;
    async_copy16(ag0, la);
    async_copy16(ag1, la + 2048);
#pragma unroll
    for (int p = 0; p < 3; p++) {
      bf16_t* lb = Bsh[p] + w * 512;
      async_copy16(bg0[p], lb);
      async_copy16(bg1[p], lb + 2048);
    }
  }
  for (int i = 0; i < 32; i++) {
    __syncthreads();
    if (i + 1 < 32) {
      const int buf = (i + 1) & 1, k0 = (i + 1) * 32;
      bf16_t* la = As + buf * 4096 + w * 512;
      async_copy16(ag0 + k0, la);
      async_copy16(ag1 + k0, la + 2048);
#pragma unroll
      for (int p = 0; p < 3; p++) {
        bf16_t* lb = Bsh[p] + buf * 4096 + w * 512;
        async_copy16(bg0[p] + k0, lb);
        async_copy16(bg1[p] + k0, lb + 2048);
      }
    }
    const bf16_t* Ar = As + (i & 1) * 4096;
    bf16x8 afr[4];
#pragma unroll
    for (int r = 0; r < 4; r++)
      afr[r] = *(const bf16x8*)&Ar[(wr * 64 + r * 16 + lm) * 32 + (quad ^ swz) * 8];
#pragma unroll
    for (int p = 0; p < 3; p++) {
      const bf16_t* Br = Bsh[p] + (i & 1) * 4096;
      bf16x8 bfr[4];
#pragma unroll
      for (int c = 0; c < 4; c++)
        bfr[c] = *(const bf16x8*)&Br[(wc * 64 + c * 16 + lm) * 32 + (quad ^ swz) * 8];
#pragma unroll
      for (int r = 0; r < 4; r++)
#pragma unroll
        for (int c = 0; c < 4; c++)
          acc[p][r][c] = __builtin_amdgcn_mfma_f32_16x16x32_bf16(afr[r], bfr[c], acc[p][r][c], 0, 0, 0);
    }
  }

  const int rowBase = m0 + wr * 64, colBase = n0 + wc * 64;
  {
    bf16_t* C = qout + (long)batch * (2048L * 1024);
#pragma unroll
    for (int r = 0; r < 4; r++) {
      const int row = rowBase + r * 16 + quad * 4;
#pragma unroll
      for (int c = 0; c < 4; c++) {
        const int col = colBase + c * 16 + lm;
        const float bv_ = bq[col];
#pragma unroll
        for (int i = 0; i < 4; i++)
          C[(long)(row + i) * 1024 + col] = (bf16_t)(acc[0][r][c][i] + bv_);
      }
    }
  }
#pragma unroll
  for (int p = 1; p < 3; p++) {
    bf16_t* C = ((p == 1) ? kT : vT) + (long)batch * (1024L * 2048);
    const float* bias = (p == 1) ? bk : bv;
#pragma unroll
    for (int r = 0; r < 4; r++) {
      const int row = rowBase + r * 16 + quad * 4;
#pragma unroll
      for (int c = 0; c < 4; c++) {
        const int col = colBase + c * 16 + lm;
        const float bv_ = bias[col];
        bf16x4 pk;
#pragma unroll
        for (int i = 0; i < 4; i++) pk[i] = (bf16_t)(acc[p][r][c][i] + bv_);
        *(bf16x4*)(C + (long)col * 2048 + row) = pk;
      }
    }
  }
}

// ---------- NT GEMM, 128x128 tile, WAVE-PRIVATE barrier-free DEPTH-4 pipeline ----------
// Each wave stages its own 64x32 A-half and 64x32 B-half into a private 32KB LDS
// slice (4 bufs x 4096 elems). No cross-wave LDS sharing -> NO s_barrier anywhere.
// Prefetch distance 3 K-steps (~750cy) to cover L2/L3 load latency in-wave:
//   prologue STAGE(0,1,2); at step i STAGE(i+3); wait vmcnt(24) -> tile i landed
//   (tiles i+1,i+2,i+3 = 24 loads still in flight). Drain 16/8/0 at the tail.
// Buffer reuse: STAGE(i+3) overwrites buf (i-1)&3, whose ds_reads retired at
// step i-1 (program order, DS queue in-order per wave).
// LDS: STATIC 128KB (4 waves x 32KB) -> 1 block/CU. gfx950 allows 160KB/WG;
// static allocation avoids the dynamic-shared >64KB attribute requirement that
// killed round 4's launch.
// OUT_MODE 0: bf16 row-major; 2: fp32 row-major (+bias). N fixed at 1024.
template<int OUT_MODE, bool HAS_BIAS, int TOTAL, int BPZ>
__global__ __launch_bounds__(256) void gemm_wp(
    const bf16_t* __restrict__ A, const bf16_t* __restrict__ B,
    void* __restrict__ C, const float* __restrict__ bias,
    int lda, int ldb, int nk, long sA, long sB, long sC, int ldc, float alpha) {
  __shared__ bf16_t Ls[4 * 16384];  // 4 waves x 4 bufs x 4096 elems = 128KB static
  const int L = blockIdx.x;
  const int V = (L & 7) * (TOTAL / 8) + (L >> 3);
  const int batch = V / BPZ;
  const int r_ = V % BPZ;
  const int n0 = (r_ & 7) * 128;
  const int m0 = (r_ >> 3) * 128;

  const int tid = threadIdx.x, lane = tid & 63, w = tid >> 6;
  const int wr = w >> 1, wc = w & 1, quad = lane >> 4, lm = lane & 15;
  const int ar = lane >> 2;
  const int ak = (((lane & 3) ^ ((ar >> 1) & 3))) * 8;
  const int swz = (lm >> 1) & 3;

  bf16_t* Lw = Ls + w * 16384;
  const bf16_t* Ab = A + (long)batch * sA;
  const bf16_t* Bb = B + (long)batch * sB;
  const bf16_t* agA = Ab + (long)(m0 + wr * 64 + ar) * lda + ak;
  const bf16_t* agB = Bb + (long)(n0 + wc * 64 + ar) * ldb + ak;

  auto STAGE = [&](int t, int b) {
    const int k0 = t * 32;
    bf16_t* d = Lw + b * 4096;
#pragma unroll
    for (int j = 0; j < 4; j++)
      async_copy16(agA + (long)j * 16 * lda + k0, d + j * 512);
#pragma unroll
    for (int j = 0; j < 4; j++)
      async_copy16(agB + (long)j * 16 * ldb + k0, d + 2048 + j * 512);
  };

  floatx4 acc[4][4];
#pragma unroll
  for (int r = 0; r < 4; r++)
#pragma unroll
    for (int c = 0; c < 4; c++) acc[r][c] = (floatx4){0.f, 0.f, 0.f, 0.f};

  STAGE(0, 0);
  STAGE(1, 1);
  STAGE(2, 2);
  for (int i = 0; i < nk; i++) {
    const int rem = nk - 1 - i;
    if (rem >= 3) {
      STAGE(i + 3, (i + 3) & 3);
      asm volatile("s_waitcnt vmcnt(24)" ::: "memory");  // tile i's 8 loads done
    } else if (rem == 2) {
      asm volatile("s_waitcnt vmcnt(16)" ::: "memory");
    } else if (rem == 1) {
      asm volatile("s_waitcnt vmcnt(8)" ::: "memory");
    } else {
      asm volatile("s_waitcnt vmcnt(0)" ::: "memory");
    }
    const bf16_t* Aw = Lw + (i & 3) * 4096;
    const bf16_t* Bw = Aw + 2048;
    bf16x8 afr[4], bfr[4];
#pragma unroll
    for (int r = 0; r < 4; r++)
      afr[r] = *(const bf16x8*)&Aw[(r * 16 + lm) * 32 + (quad ^ swz) * 8];
#pragma unroll
    for (int c = 0; c < 4; c++)
      bfr[c] = *(const bf16x8*)&Bw[(c * 16 + lm) * 32 + (quad ^ swz) * 8];
#pragma unroll
    for (int r = 0; r < 4; r++)
#pragma unroll
      for (int c = 0; c < 4; c++)
        acc[r][c] = __builtin_amdgcn_mfma_f32_16x16x32_bf16(afr[r], bfr[c], acc[r][c], 0, 0, 0);
  }

  const int rowBase = m0 + wr * 64, colBase = n0 + wc * 64;
  if (OUT_MODE == 0) {
    bf16_t* Cb = (bf16_t*)C + (long)batch * sC;
#pragma unroll
    for (int r = 0; r < 4; r++) {
      const int row = rowBase + r * 16 + quad * 4;
#pragma unroll
      for (int c = 0; c < 4; c++) {
        const int col = colBase + c * 16 + lm;
        const float bv_ = HAS_BIAS ? bias[col] : 0.f;
#pragma unroll
        for (int i = 0; i < 4; i++)
          Cb[(long)(row + i) * ldc + col] = (bf16_t)(acc[r][c][i] * alpha + bv_);
      }
    }
  } else {
    float* Cf = (float*)C + (long)batch * sC;
#pragma unroll
    for (int r = 0; r < 4; r++) {
      const int row = rowBase + r * 16 + quad * 4;
#pragma unroll
      for (int c = 0; c < 4; c++) {
        const int col = colBase + c * 16 + lm;
        const float bv_ = HAS_BIAS ? bias[col] : 0.f;
#pragma unroll
        for (int i = 0; i < 4; i++)
          Cf[(long)(row + i) * ldc + col] = acc[r][c][i] * alpha + bv_;
      }
    }
  }
}

extern "C" void kernel_launch(void* const* d_in, const int* in_sizes, int n_in,
                              void* d_out, int out_size, void* d_ws, size_t ws_size,
                              hipStream_t stream) {
  const float* x  = (const float*)d_in[0];
  const float* Wq = (const float*)d_in[1];
  const float* bq = (const float*)d_in[2];
  const float* Wk = (const float*)d_in[3];
  const float* bk = (const float*)d_in[4];
  const float* Wv = (const float*)d_in[5];
  const float* bv = (const float*)d_in[6];
  const float* Wo = (const float*)d_in[7];
  const float* bo = (const float*)d_in[8];
  float* out = (float*)d_out;

  const long NX = 8192L * 1024;      // 8M elems
  const long NW = 1024L * 1024;      // 1M elems

  bf16_t* ws  = (bf16_t*)d_ws;
  bf16_t* xb  = ws;                  // NX
  bf16_t* Wqb = xb + NX;
  bf16_t* Wkb = Wqb + NW;
  bf16_t* Wvb = Wkb + NW;
  bf16_t* Wob = Wvb + NW;
  bf16_t* qb  = Wob + NW;            // NX
  bf16_t* kT  = qb + NX;             // NX [B][E][S]
  bf16_t* vT  = kT + NX;             // NX [B][E][S]
  // reuse (stream-ordered):
  bf16_t* MtTb = xb;                 // 4M: [B][f][e], xb dead after qkv3
  bf16_t* Gb   = vT;                 // 4M: [B][i][f], vT dead after Mt gemm

  CvtArgs ca;
  ca.seg[0] = {x,  xb,  NX};
  ca.seg[1] = {Wq, Wqb, NW};
  ca.seg[2] = {Wk, Wkb, NW};
  ca.seg[3] = {Wv, Wvb, NW};
  ca.seg[4] = {Wo, Wob, NW};
  cvt_multi<<<dim3(2048, 5), 256, 0, stream>>>(ca);

  // q / kT / vT fused, LDS dbuf (round-5 proven structure)
  qkv3<<<dim3(512), 256, 0, stream>>>(xb, Wqb, Wkb, Wvb, bq, bk, bv, qb, kT, vT);

  // MtT[f,e] = 0.125 * sum_t kT[f,t]*vT[e,t]; K=2048 (nk=64), 256 blocks (1/CU)
  gemm_wp<0, false, 256, 64><<<dim3(256), 256, 0, stream>>>(
      kT, vT, MtTb, nullptr, 2048, 2048, 64,
      1024L * 2048, 1024L * 2048, 1024L * 1024, 1024, 0.125f);

  // G[i,f] = sum_e Wo[i,e] * MtT[f,e]; 256 blocks (1/CU)
  gemm_wp<0, false, 256, 64><<<dim3(256), 256, 0, stream>>>(
      Wob, MtTb, Gb, nullptr, 1024, 1024, 32,
      0L, 1024L * 1024, 1024L * 1024, 1024, 1.0f);

  // out[s,i] = sum_f q[s,f] * G[i,f] + bo[i]; 512 blocks (1/CU, 2 passes)
  gemm_wp<2, true, 512, 128><<<dim3(512), 256, 0, stream>>>(
      qb, Gb, out, bo, 1024, 1024, 32,
      2048L * 1024, 1024L * 1024, 2048L * 1024, 1024, 1.0f);
}